// Round 6
// baseline (24.666 us; speedup 1.0000x reference)
//
#include <hip/hip_runtime.h>

// ROI max-pool: [512*256 planes, 14x14] fp32 -> [planes, 7x7] fp32.
// Exact 2x2 non-overlapping max windows. Memory-bound (~103 MB in, ~26 MB out).
//
// R6: wave-independent staging via global_load_lds (16B direct-to-LDS DMA,
// no VGPR round trip). Each wave stages its OWN 4 planes (196 x 16B chunks,
// linear LDS dest = uniform base + lane*16) and consumes them after its own
// s_waitcnt vmcnt(0) -- no __syncthreads needed (wave-synchronous LDS).
// Stores: 16B regular (R4 proved NT regresses; R5 proved 16B >= dword).

typedef float f32x4 __attribute__((ext_vector_type(4)));

#define PPB   16          // planes per block (4 per wave)
#define BLOCK 256

__global__ __launch_bounds__(BLOCK)
void ROIPooling_86466281603470_kernel(const float* __restrict__ in,
                                      float* __restrict__ out) {
    __shared__ float lds[PPB * 196];   // 12544 B

    const int lane = threadIdx.x & 63;
    const int w    = threadIdx.x >> 6;           // wave id 0..3
    const size_t pb = (size_t)blockIdx.x * PPB;

    // wave's 4 planes = 784 floats = 196 x 16B chunks
    const float* gbase = in + pb * 196 + w * 784;
    float*       lbase = lds + w * 784;

    // ---- stage: 3 full-wave DMA iters + 4-lane tail (196 = 3*64 + 4) ----
    #pragma unroll
    for (int k = 0; k < 3; ++k) {
        __builtin_amdgcn_global_load_lds(
            (const __attribute__((address_space(1))) void*)(gbase + k * 256 + lane * 4),
            (__attribute__((address_space(3))) void*)(lbase + k * 256),
            16, 0, 0);
    }
    if (lane < 4) {
        __builtin_amdgcn_global_load_lds(
            (const __attribute__((address_space(1))) void*)(gbase + 768 + lane * 4),
            (__attribute__((address_space(3))) void*)(lbase + 768),
            16, 0, 0);
    }
    asm volatile("s_waitcnt vmcnt(0)" ::: "memory");  // wave-local; no barrier

    // ---- compute: lanes 0..48 each produce 4 outputs + one 16B store ----
    if (lane < 49) {
        f32x4 r;
        #pragma unroll
        for (int q = 0; q < 4; ++q) {
            int o   = 4 * lane + q;    // [0,196) within wave's 4 planes
            int p   = o / 49;
            int rem = o - p * 49;
            int i   = rem / 7;
            int j   = rem - i * 7;
            const float* base = lbase + p * 196 + i * 28 + 2 * j;
            float2 a = *reinterpret_cast<const float2*>(base);        // row 2i
            float2 b = *reinterpret_cast<const float2*>(base + 14);   // row 2i+1
            r[q] = fmaxf(fmaxf(a.x, a.y), fmaxf(b.x, b.y));
        }
        f32x4* out4 = reinterpret_cast<f32x4*>(out + pb * 49 + w * 196);
        out4[lane] = r;
    }
}

extern "C" void kernel_launch(void* const* d_in, const int* in_sizes, int n_in,
                              void* d_out, int out_size, void* d_ws, size_t ws_size,
                              hipStream_t stream) {
    const float* in = (const float*)d_in[0];
    float* out = (float*)d_out;
    int n_planes = out_size / 49;            // 512*256 = 131072, divisible by PPB
    int grid = n_planes / PPB;               // 8192 blocks
    ROIPooling_86466281603470_kernel<<<grid, BLOCK, 0, stream>>>(in, out);
}